// Round 6
// baseline (170.852 us; speedup 1.0000x reference)
//
#include <hip/hip_runtime.h>

// WaveletProcessor: 4x [Conv1d(64,64,k) -> ReLU -> Conv1d(64,64,1)], softmax-weighted sum.
// Device buffers are float32. Compute: bf16 MFMA (16x16x32 conv1, 16x16x16 conv2), fp32 accum.
// Round 6: nt=8 (128 L-cols/wave, NT=512). 32 independent MFMAs per (dk,ks) phase
// (~155 cyc issue per load-drain point), half the weight-load instructions per output,
// 1 block/CU so the 4 waves share frag L1. 256 AGPR + ~100 VGPR -> 1 wave/SIMD (deliberate:
// r3->r4 showed ILP beats TLP here). Dynamic LDS 74.9 KB. One barrier per block.

constexpr int Bn = 32, Ln = 8192;
constexpr int NT = 512;          // length-tile per workgroup (4 waves x 128)
constexpr int HALO = 4;          // max pad
constexpr int XROWS = NT + 2 * HALO;   // 520
constexpr int RS = 72;           // LDS row stride in ushorts (144B)
constexpr int XS_BYTES = XROWS * RS * 2;   // 74880

using bf16x8 = __attribute__((ext_vector_type(8))) __bf16;
using f32x4  = __attribute__((ext_vector_type(4))) float;
using u16x8  = __attribute__((ext_vector_type(8))) unsigned short;
using u16x4  = __attribute__((ext_vector_type(4))) unsigned short;
using s16x4  = __attribute__((ext_vector_type(4))) short;

struct Ptrs {
    const float* x;
    const float* rw;
    const float* w1[4];
    const float* b1[4];
    const float* w2[4];
    const float* b2[4];
};

__device__ __forceinline__ unsigned short f2bf(float f) {
    __bf16 h = (__bf16)f;                       // native cvt, RNE
    return __builtin_bit_cast(unsigned short, h);
}

#if defined(__has_builtin)
#  if __has_builtin(__builtin_amdgcn_mfma_f32_16x16x16bf16_1k)
#    define HAVE_MFMA16 1
#  endif
#endif

__device__ __forceinline__ void mfma16(f32x4& c, u16x4 a, u16x4 b) {
#ifdef HAVE_MFMA16
    c = __builtin_amdgcn_mfma_f32_16x16x16bf16_1k(
            __builtin_bit_cast(s16x4, a), __builtin_bit_cast(s16x4, b), c, 0, 0, 0);
#else
    asm("v_mfma_f32_16x16x16_bf16 %0, %1, %2, %0" : "+v"(c) : "v"(a), "v"(b));
#endif
}

// ---------------- prep: softmax + weight fragment pre-transposition ----------------
// d_ws layout: [0..3] float softmax w; [4..67] float fused bias (sum_i w_i*b2_i);
// at byte 512, bf16 fragments:
//   F1 (conv1 A, 16x16x32): 160 blocks x 512 elems; branch bases {0,24,48,88} blocks,
//     block = dk*8 + ks*4 + mt; elem = lane*8+j; co=mt*16+(lane&15), ci=ks*32+(lane>>4)*8+j.
//   F2 (conv2 A, 16x16x16): base elem 81920; branch br at +br*4096; frag (kb,mt) at
//     +(kb*4+mt)*256; elem = lane*4+j; co2=mt*16+(lane&15), ci=kb*16+(lane>>4)*4+j;
//     value pre-scaled by softmax w[br].
__global__ void prep_kernel(Ptrs p, unsigned short* __restrict__ frag, float* __restrict__ hdr) {
    int tid = threadIdx.x;
    float v0 = p.rw[0], v1 = p.rw[1], v2 = p.rw[2], v3 = p.rw[3];
    float m = fmaxf(fmaxf(v0, v1), fmaxf(v2, v3));
    float e0 = expf(v0 - m), e1 = expf(v1 - m), e2 = expf(v2 - m), e3 = expf(v3 - m);
    float s = e0 + e1 + e2 + e3;
    float w[4] = {e0 / s, e1 / s, e2 / s, e3 / s};

    if (blockIdx.x == 0) {
        if (tid < 4) hdr[tid] = w[tid];
        if (tid < 64) {
            float fb = 0.f;
            #pragma unroll
            for (int i = 0; i < 4; i++) fb += w[i] * p.b2[i][tid];
            hdr[4 + tid] = fb;
        }
    }

    const int kk[4] = {3, 3, 5, 9};
    const int f1blocks[4] = {24, 24, 40, 72};

    for (int idx = blockIdx.x * blockDim.x + tid; idx < 81920 + 16384; idx += gridDim.x * blockDim.x) {
        unsigned short val;
        if (idx < 81920) {
            int blk = idx >> 9;
            int e = idx & 511;
            int lane = e >> 3, j = e & 7;
            int br = 0, rem = blk;
            while (rem >= f1blocks[br]) { rem -= f1blocks[br]; br++; }
            int dk = rem >> 3, ks = (rem >> 2) & 1, mt = rem & 3;
            int co = mt * 16 + (lane & 15);
            int ci = ks * 32 + (lane >> 4) * 8 + j;
            val = f2bf(p.w1[br][(co * 64 + ci) * kk[br] + dk]);
        } else {
            int e2 = idx - 81920;
            int br = e2 >> 12;
            int fi = (e2 >> 8) & 15;       // kb*4 + mt
            int kb = fi >> 2, mt = fi & 3;
            int e = e2 & 255;
            int lane = e >> 2, j = e & 3;
            int co = mt * 16 + (lane & 15);
            int ci = kb * 16 + (lane >> 4) * 4 + j;
            val = f2bf(w[br] * p.w2[br][co * 64 + ci]);
        }
        frag[idx] = val;
    }
}

// ---------------- main kernel ----------------
template <int KK, int PP>
__device__ __forceinline__ void do_branch(const unsigned short* __restrict__ frag1,
                                          const unsigned short* __restrict__ frag2,
                                          const float* __restrict__ b1,
                                          const unsigned short* xs,
                                          int lane, int wl0, f32x4 (&fused)[4][8]) {
    int col = lane & 15, kg = lane >> 4;

    // conv1 accumulators initialized to b1[co]
    f32x4 acc[4][8];
    #pragma unroll
    for (int mt = 0; mt < 4; mt++) {
        f32x4 bi;
        #pragma unroll
        for (int r = 0; r < 4; r++) bi[r] = b1[mt * 16 + kg * 4 + r];
        #pragma unroll
        for (int nt = 0; nt < 8; nt++) acc[mt][nt] = bi;
    }

    #pragma unroll
    for (int dk = 0; dk < KK; dk++) {
        #pragma unroll
        for (int ks = 0; ks < 2; ks++) {
            bf16x8 bfr[8];
            #pragma unroll
            for (int nt = 0; nt < 8; nt++) {
                int row = wl0 + nt * 16 + col + (HALO - PP) + dk;
                bfr[nt] = __builtin_bit_cast(bf16x8, *(const u16x8*)&xs[row * RS + ks * 32 + kg * 8]);
            }
            const unsigned short* fp = frag1 + (size_t)(dk * 8 + ks * 4) * 512 + lane * 8;
            #pragma unroll
            for (int mt = 0; mt < 4; mt++) {
                bf16x8 afr = __builtin_bit_cast(bf16x8, *(const u16x8*)(fp + (size_t)mt * 512));
                #pragma unroll
                for (int nt = 0; nt < 8; nt++)
                    acc[mt][nt] = __builtin_amdgcn_mfma_f32_16x16x32_bf16(afr, bfr[nt], acc[mt][nt], 0, 0, 0);
            }
        }
    }

    // conv2 (1x1) straight from registers: ReLU(acc) repacked in-lane is the
    // 16x16x16 B-fragment (conv1 D row co == conv2 k ci; col l unchanged).
    #pragma unroll
    for (int kb = 0; kb < 4; kb++) {
        u16x4 hb[8];
        #pragma unroll
        for (int nt = 0; nt < 8; nt++) {
            u16x4 h;
            #pragma unroll
            for (int r = 0; r < 4; r++) h[r] = f2bf(fmaxf(acc[kb][nt][r], 0.f));
            hb[nt] = h;
        }
        const unsigned short* fp2 = frag2 + (size_t)kb * 4 * 256 + lane * 4;
        #pragma unroll
        for (int mt = 0; mt < 4; mt++) {
            u16x4 afr = *(const u16x4*)(fp2 + (size_t)mt * 256);
            #pragma unroll
            for (int nt = 0; nt < 8; nt++)
                mfma16(fused[mt][nt], afr, hb[nt]);
        }
    }
}

__global__ __launch_bounds__(256, 1) void wavelet_main(Ptrs p,
                                                       const unsigned short* __restrict__ frag,
                                                       const float* __restrict__ hdr,
                                                       float* __restrict__ out) {
    extern __shared__ unsigned short xs[];   // XROWS*RS ushorts = 74880 B

    int tid = threadIdx.x;
    int b = blockIdx.x >> 4;           // 16 tiles per batch
    int t0 = (blockIdx.x & 15) * NT;

    // stage x tile (+halo) into LDS as bf16, zero-padded at batch edges
    {
        int c0 = (tid & 7) * 8;
        int rbase = tid >> 3;          // 0..31
        #pragma unroll
        for (int it = 0; it < 17; it++) {
            int rr = it * 32 + rbase;
            if (rr < XROWS) {
                int l = t0 + rr - HALO;
                u16x8 v = {0, 0, 0, 0, 0, 0, 0, 0};
                if (l >= 0 && l < Ln) {
                    const float* src = &p.x[((size_t)b * Ln + l) * 64 + c0];
                    f32x4 a0 = *(const f32x4*)src;
                    f32x4 a1 = *(const f32x4*)(src + 4);
                    #pragma unroll
                    for (int r = 0; r < 4; r++) { v[r] = f2bf(a0[r]); v[4 + r] = f2bf(a1[r]); }
                }
                *(u16x8*)&xs[rr * RS + c0] = v;
            }
        }
    }

    int lane = tid & 63;
    int wl0 = (tid >> 6) * 128;   // each wave owns a 128-wide L-chunk
    int kg = lane >> 4;

    // fused accumulator init = sum_i w_i * b2_i[co]
    f32x4 fused[4][8];
    #pragma unroll
    for (int mt = 0; mt < 4; mt++) {
        f32x4 fi;
        #pragma unroll
        for (int r = 0; r < 4; r++) fi[r] = hdr[4 + mt * 16 + kg * 4 + r];
        #pragma unroll
        for (int nt = 0; nt < 8; nt++) fused[mt][nt] = fi;
    }

    __syncthreads();   // xs ready — the only barrier

    do_branch<3, 1>(frag + (size_t)0 * 512,  frag + 81920 + (size_t)0 * 4096, p.b1[0], xs, lane, wl0, fused);
    do_branch<3, 1>(frag + (size_t)24 * 512, frag + 81920 + (size_t)1 * 4096, p.b1[1], xs, lane, wl0, fused);
    do_branch<5, 2>(frag + (size_t)48 * 512, frag + 81920 + (size_t)2 * 4096, p.b1[2], xs, lane, wl0, fused);
    do_branch<9, 4>(frag + (size_t)88 * 512, frag + 81920 + (size_t)3 * 4096, p.b1[3], xs, lane, wl0, fused);

#ifndef HAVE_MFMA16
    asm volatile("s_nop 7\ns_nop 7");   // MFMA->VALU hazard guard for asm path
#endif

    // write output: out[b][l][c] = fused[c][l], fp32, channel-contiguous float4
    int col = lane & 15;
    #pragma unroll
    for (int mt = 0; mt < 4; mt++) {
        #pragma unroll
        for (int nt = 0; nt < 8; nt++) {
            int l = t0 + wl0 + nt * 16 + col;
            *(f32x4*)&out[((size_t)b * Ln + l) * 64 + mt * 16 + kg * 4] = fused[mt][nt];
        }
    }
}

extern "C" void kernel_launch(void* const* d_in, const int* in_sizes, int n_in,
                              void* d_out, int out_size, void* d_ws, size_t ws_size,
                              hipStream_t stream) {
    Ptrs p;
    p.x  = (const float*)d_in[0];
    p.rw = (const float*)d_in[1];
    for (int i = 0; i < 4; i++) {
        p.w1[i] = (const float*)d_in[2 + 4 * i];
        p.b1[i] = (const float*)d_in[3 + 4 * i];
        p.w2[i] = (const float*)d_in[4 + 4 * i];
        p.b2[i] = (const float*)d_in[5 + 4 * i];
    }
    float* hdr = (float*)d_ws;
    unsigned short* frag = (unsigned short*)((char*)d_ws + 512);

    // allow >64KB dynamic LDS (74880 B); host-side attribute set, not a stream op
    static bool attr_done = false;
    if (!attr_done) {
        hipFuncSetAttribute((const void*)wavelet_main,
                            hipFuncAttributeMaxDynamicSharedMemorySize, XS_BYTES);
        attr_done = true;
    }

    hipLaunchKernelGGL(prep_kernel, dim3(96), dim3(256), 0, stream, p, frag, hdr);
    hipLaunchKernelGGL(wavelet_main, dim3(Bn * (Ln / NT)), dim3(256), XS_BYTES, stream, p, frag, hdr,
                       (float*)d_out);
}

// Round 7
// 75.071 us; speedup vs baseline: 2.2759x; 2.2759x over previous
//
#include <hip/hip_runtime.h>

// WaveletProcessor: 4x [Conv1d(64,64,k) -> ReLU -> Conv1d(64,64,1)], softmax-weighted sum.
// Device buffers are float32. Compute: bf16 MFMA (16x16x32 conv1, 16x16x16 conv2), fp32 accum.
// Round 7: weights streamed through a 2x8KB LDS ping-pong via global_load_lds with
// counted vmcnt(2) + raw s_barrier (T3/T4). Weight slices laid out in d_ws in exact
// consumption order (24 slices x 8KB). Biases staged in LDS (keeps vmcnt counts clean).
// NT=256, nt=4/wave, 2 waves/SIMD.

constexpr int Bn = 32, Ln = 8192;
constexpr int NT = 256;          // length-tile per workgroup (4 waves x 64)
constexpr int HALO = 4;
constexpr int XROWS = NT + 2 * HALO;   // 264
constexpr int RS = 72;           // LDS row stride in ushorts (144B -> 2-way alias, free)
constexpr int NSLICE = 24;       // 4+4+6+10 weight slices of 8KB (4096 ushorts)

using bf16x8 = __attribute__((ext_vector_type(8))) __bf16;
using f32x4  = __attribute__((ext_vector_type(4))) float;
using u16x8  = __attribute__((ext_vector_type(8))) unsigned short;
using u16x4  = __attribute__((ext_vector_type(4))) unsigned short;
using s16x4  = __attribute__((ext_vector_type(4))) short;

struct Ptrs {
    const float* x;
    const float* rw;
    const float* w1[4];
    const float* b1[4];
    const float* w2[4];
    const float* b2[4];
};

__device__ __forceinline__ unsigned short f2bf(float f) {
    __bf16 h = (__bf16)f;
    return __builtin_bit_cast(unsigned short, h);
}

#if defined(__has_builtin)
#  if __has_builtin(__builtin_amdgcn_mfma_f32_16x16x16bf16_1k)
#    define HAVE_MFMA16 1
#  endif
#endif

__device__ __forceinline__ void mfma16(f32x4& c, u16x4 a, u16x4 b) {
#ifdef HAVE_MFMA16
    c = __builtin_amdgcn_mfma_f32_16x16x16bf16_1k(
            __builtin_bit_cast(s16x4, a), __builtin_bit_cast(s16x4, b), c, 0, 0, 0);
#else
    asm("v_mfma_f32_16x16x16_bf16 %0, %1, %2, %0" : "+v"(c) : "v"(a), "v"(b));
#endif
}

// issue async stage of slice s into wbuf[s&1]: 2 x 16B per thread (8KB per block)
__device__ __forceinline__ void stage_slice(const unsigned short* __restrict__ frag,
                                            unsigned short* wbuf, int s, int tid) {
    const unsigned short* g = frag + (size_t)s * 4096 + tid * 8;
    unsigned short* l = wbuf + (s & 1) * 4096 + tid * 8;
    __builtin_amdgcn_global_load_lds(
        (const __attribute__((address_space(1))) unsigned int*)g,
        (__attribute__((address_space(3))) unsigned int*)l, 16, 0, 0);
    __builtin_amdgcn_global_load_lds(
        (const __attribute__((address_space(1))) unsigned int*)(g + 2048),
        (__attribute__((address_space(3))) unsigned int*)(l + 2048), 16, 0, 0);
}

// wait for current slice (2 newer loads may stay in flight), then block barrier
__device__ __forceinline__ void wait_bar_vm2() {
    asm volatile("s_waitcnt vmcnt(2)" ::: "memory");
    __builtin_amdgcn_sched_barrier(0);
    __builtin_amdgcn_s_barrier();
    __builtin_amdgcn_sched_barrier(0);
}
__device__ __forceinline__ void wait_bar_vm0() {
    asm volatile("s_waitcnt vmcnt(0)" ::: "memory");
    __builtin_amdgcn_sched_barrier(0);
    __builtin_amdgcn_s_barrier();
    __builtin_amdgcn_sched_barrier(0);
}
__device__ __forceinline__ void end_bar() {
    __builtin_amdgcn_sched_barrier(0);
    __builtin_amdgcn_s_barrier();
    __builtin_amdgcn_sched_barrier(0);
}

// ---------------- prep: softmax + weights into slice-ordered fragments ----------------
// d_ws: [0..3] float softmax w; [4..67] float fused bias (sum_i w_i*b2_i);
// at byte 512: 24 slices x 4096 ushorts (8KB), consumption order:
//   branch br slices at sbase[br]={0,4,8,14}: kk[br] F1 slices then 1 F2 slice.
//   F1 slice (br,dk): e = (ks*4+mt)*512 + lane*8 + j;
//     co=mt*16+(lane&15), ci=ks*32+(lane>>4)*8+j; val = W1[co][ci][dk].
//   F2 slice (br):     e = (kb*4+mt)*256 + lane*4 + j;
//     co=mt*16+(lane&15), ci=kb*16+(lane>>4)*4+j; val = w[br]*W2[co][ci].
__global__ void prep_kernel(Ptrs p, unsigned short* __restrict__ frag, float* __restrict__ hdr) {
    int tid = threadIdx.x;
    float v0 = p.rw[0], v1 = p.rw[1], v2 = p.rw[2], v3 = p.rw[3];
    float m = fmaxf(fmaxf(v0, v1), fmaxf(v2, v3));
    float e0 = expf(v0 - m), e1 = expf(v1 - m), e2 = expf(v2 - m), e3 = expf(v3 - m);
    float s = e0 + e1 + e2 + e3;
    float w[4] = {e0 / s, e1 / s, e2 / s, e3 / s};

    if (blockIdx.x == 0) {
        if (tid < 4) hdr[tid] = w[tid];
        if (tid < 64) {
            float fb = 0.f;
            #pragma unroll
            for (int i = 0; i < 4; i++) fb += w[i] * p.b2[i][tid];
            hdr[4 + tid] = fb;
        }
    }

    const int kk[4] = {3, 3, 5, 9};
    const int sbase[4] = {0, 4, 8, 14};

    for (int idx = blockIdx.x * blockDim.x + tid; idx < NSLICE * 4096; idx += gridDim.x * blockDim.x) {
        int sl = idx >> 12;
        int e = idx & 4095;
        int br = 3;
        #pragma unroll
        for (int i = 2; i >= 0; i--) if (sl < sbase[i + 1]) br = i;
        int local = sl - sbase[br];
        unsigned short val;
        if (local < kk[br]) {       // F1 slice, dk = local
            int blk = e >> 9;       // ks*4 + mt
            int ks = blk >> 2, mt = blk & 3;
            int sub = e & 511;
            int lane = sub >> 3, j = sub & 7;
            int co = mt * 16 + (lane & 15);
            int ci = ks * 32 + (lane >> 4) * 8 + j;
            val = f2bf(p.w1[br][(co * 64 + ci) * kk[br] + local]);
        } else {                    // F2 slice
            int fi = e >> 8;        // kb*4 + mt
            int kb = fi >> 2, mt = fi & 3;
            int sub = e & 255;
            int lane = sub >> 2, j = sub & 3;
            int co = mt * 16 + (lane & 15);
            int ci = kb * 16 + (lane >> 4) * 4 + j;
            val = f2bf(w[br] * p.w2[br][co * 64 + ci]);
        }
        frag[idx] = val;
    }
}

// ---------------- main kernel ----------------
template <int KK, int PP, int S0>
__device__ __forceinline__ void do_branch(const unsigned short* __restrict__ frag,
                                          unsigned short* wbuf,
                                          const float* b1l,
                                          const unsigned short* xs,
                                          int tid, int lane, int wl0,
                                          f32x4 (&fused)[4][4]) {
    int col = lane & 15, kg = lane >> 4;

    f32x4 acc[4][4];
    #pragma unroll
    for (int mt = 0; mt < 4; mt++)
        #pragma unroll
        for (int nt = 0; nt < 4; nt++)
            acc[mt][nt] = f32x4{0.f, 0.f, 0.f, 0.f};

    #pragma unroll
    for (int dk = 0; dk < KK; dk++) {
        stage_slice(frag, wbuf, S0 + dk + 1, tid);   // prefetch next slice
        wait_bar_vm2();                               // slice S0+dk ready for all waves
        const unsigned short* wb = wbuf + ((S0 + dk) & 1) * 4096;
        #pragma unroll
        for (int ks = 0; ks < 2; ks++) {
            bf16x8 bfr[4];
            #pragma unroll
            for (int nt = 0; nt < 4; nt++) {
                int row = wl0 + nt * 16 + col + (HALO - PP) + dk;
                bfr[nt] = __builtin_bit_cast(bf16x8, *(const u16x8*)&xs[row * RS + ks * 32 + kg * 8]);
            }
            #pragma unroll
            for (int mt = 0; mt < 4; mt++) {
                bf16x8 afr = __builtin_bit_cast(bf16x8,
                    *(const u16x8*)(wb + (ks * 4 + mt) * 512 + lane * 8));
                #pragma unroll
                for (int nt = 0; nt < 4; nt++)
                    acc[mt][nt] = __builtin_amdgcn_mfma_f32_16x16x32_bf16(afr, bfr[nt], acc[mt][nt], 0, 0, 0);
            }
        }
        end_bar();                                    // all waves done with this buffer
    }

    constexpr int SF2 = S0 + KK;
    constexpr bool HN = (SF2 + 1 < NSLICE);
    if constexpr (HN) stage_slice(frag, wbuf, SF2 + 1, tid);

    f32x4 bv[4];
    #pragma unroll
    for (int mt = 0; mt < 4; mt++) bv[mt] = *(const f32x4*)&b1l[mt * 16 + kg * 4];

    if constexpr (HN) wait_bar_vm2(); else wait_bar_vm0();
    const unsigned short* wb2 = wbuf + (SF2 & 1) * 4096;

    // conv2 (1x1) from registers: ReLU(acc+b1) repacked in-lane is the 16x16x16 B-frag.
    #pragma unroll
    for (int kb = 0; kb < 4; kb++) {
        u16x4 hb[4];
        #pragma unroll
        for (int nt = 0; nt < 4; nt++) {
            u16x4 h;
            #pragma unroll
            for (int r = 0; r < 4; r++) h[r] = f2bf(fmaxf(acc[kb][nt][r] + bv[kb][r], 0.f));
            hb[nt] = h;
        }
        #pragma unroll
        for (int mt = 0; mt < 4; mt++) {
            u16x4 afr = *(const u16x4*)(wb2 + (kb * 4 + mt) * 256 + lane * 4);
            #pragma unroll
            for (int nt = 0; nt < 4; nt++)
                mfma16(fused[mt][nt], afr, hb[nt]);
        }
    }
    if constexpr (HN) end_bar();
}

__global__ __launch_bounds__(256, 2) void wavelet_main(Ptrs p,
                                                       const unsigned short* __restrict__ frag,
                                                       const float* __restrict__ hdr,
                                                       float* __restrict__ out) {
    __shared__ unsigned short xs[XROWS * RS];   // 38016 B
    __shared__ unsigned short wbuf[2 * 4096];   // 16384 B ping-pong for weight slices
    __shared__ float b1l[4 * 64];               // conv1 biases
    __shared__ float fbl[64];                   // fused bias sum_i w_i*b2_i

    int tid = threadIdx.x;
    int b = blockIdx.x >> 5;
    int t0 = (blockIdx.x & 31) * NT;

    stage_slice(frag, wbuf, 0, tid);            // earliest prefetch of slice 0

    // stage x tile (+halo) into LDS as bf16, zero-padded at batch edges
    {
        int c0 = (tid & 7) * 8;
        int rbase = tid >> 3;
        #pragma unroll
        for (int it = 0; it < 9; it++) {
            int rr = it * 32 + rbase;
            if (rr < XROWS) {
                int l = t0 + rr - HALO;
                u16x8 v = {0, 0, 0, 0, 0, 0, 0, 0};
                if (l >= 0 && l < Ln) {
                    const float* src = &p.x[((size_t)b * Ln + l) * 64 + c0];
                    f32x4 a0 = *(const f32x4*)src;
                    f32x4 a1 = *(const f32x4*)(src + 4);
                    #pragma unroll
                    for (int r = 0; r < 4; r++) { v[r] = f2bf(a0[r]); v[4 + r] = f2bf(a1[r]); }
                }
                *(u16x8*)&xs[rr * RS + c0] = v;
            }
        }
    }
    b1l[tid] = p.b1[tid >> 6][tid & 63];
    if (tid < 64) fbl[tid] = hdr[4 + tid];

    __syncthreads();   // drains all prologue vmem (incl. slice 0) + barrier

    int lane = tid & 63;
    int wl0 = (tid >> 6) * 64;
    int kg = lane >> 4;

    f32x4 fused[4][4];
    #pragma unroll
    for (int mt = 0; mt < 4; mt++)
        #pragma unroll
        for (int nt = 0; nt < 4; nt++)
            fused[mt][nt] = f32x4{0.f, 0.f, 0.f, 0.f};

    do_branch<3, 1, 0 >(frag, wbuf, b1l + 0 * 64, xs, tid, lane, wl0, fused);
    do_branch<3, 1, 4 >(frag, wbuf, b1l + 1 * 64, xs, tid, lane, wl0, fused);
    do_branch<5, 2, 8 >(frag, wbuf, b1l + 2 * 64, xs, tid, lane, wl0, fused);
    do_branch<9, 4, 14>(frag, wbuf, b1l + 3 * 64, xs, tid, lane, wl0, fused);

#ifndef HAVE_MFMA16
    asm volatile("s_nop 7\ns_nop 7");   // MFMA->VALU hazard guard for asm path
#endif

    // epilogue: add fused bias, write out[b][l][c] fp32 channel-contiguous
    int col = lane & 15;
    f32x4 fb[4];
    #pragma unroll
    for (int mt = 0; mt < 4; mt++) fb[mt] = *(const f32x4*)&fbl[mt * 16 + kg * 4];
    #pragma unroll
    for (int mt = 0; mt < 4; mt++) {
        #pragma unroll
        for (int nt = 0; nt < 4; nt++) {
            int l = t0 + wl0 + nt * 16 + col;
            f32x4 v;
            #pragma unroll
            for (int r = 0; r < 4; r++) v[r] = fused[mt][nt][r] + fb[mt][r];
            *(f32x4*)&out[((size_t)b * Ln + l) * 64 + mt * 16 + kg * 4] = v;
        }
    }
}

extern "C" void kernel_launch(void* const* d_in, const int* in_sizes, int n_in,
                              void* d_out, int out_size, void* d_ws, size_t ws_size,
                              hipStream_t stream) {
    Ptrs p;
    p.x  = (const float*)d_in[0];
    p.rw = (const float*)d_in[1];
    for (int i = 0; i < 4; i++) {
        p.w1[i] = (const float*)d_in[2 + 4 * i];
        p.b1[i] = (const float*)d_in[3 + 4 * i];
        p.w2[i] = (const float*)d_in[4 + 4 * i];
        p.b2[i] = (const float*)d_in[5 + 4 * i];
    }
    float* hdr = (float*)d_ws;
    unsigned short* frag = (unsigned short*)((char*)d_ws + 512);

    hipLaunchKernelGGL(prep_kernel, dim3(96), dim3(256), 0, stream, p, frag, hdr);
    hipLaunchKernelGGL(wavelet_main, dim3(Bn * (Ln / NT)), dim3(256), 0, stream, p, frag, hdr,
                       (float*)d_out);
}

// Round 8
// 69.401 us; speedup vs baseline: 2.4618x; 1.0817x over previous
//
#include <hip/hip_runtime.h>

// WaveletProcessor: 4x [Conv1d(64,64,k) -> ReLU -> Conv1d(64,64,1)], softmax-weighted sum.
// Device buffers are float32. Compute: bf16 MFMA (16x16x32 conv1, 16x16x16 conv2), fp32 accum.
// Round 8: weight stream through a 4-deep (4x8KB) LDS ring via global_load_lds.
// ONE raw s_barrier per slice (24 total, was 48) and vmcnt(4) counted waits with
// 3-slice-deep prefetch (waits ~0). Slice order matches consumption exactly.
// NT=256, nt=4/wave, 2 blocks/CU.

constexpr int Bn = 32, Ln = 8192;
constexpr int NT = 256;          // length-tile per workgroup (4 waves x 64)
constexpr int HALO = 4;
constexpr int XROWS = NT + 2 * HALO;   // 264
constexpr int RS = 72;           // LDS row stride in ushorts (144B -> 2-way alias, free)
constexpr int NSLICE = 24;       // 4+4+6+10 weight slices of 8KB (4096 ushorts)

using bf16x8 = __attribute__((ext_vector_type(8))) __bf16;
using f32x4  = __attribute__((ext_vector_type(4))) float;
using u16x8  = __attribute__((ext_vector_type(8))) unsigned short;
using u16x4  = __attribute__((ext_vector_type(4))) unsigned short;
using s16x4  = __attribute__((ext_vector_type(4))) short;

struct Ptrs {
    const float* x;
    const float* rw;
    const float* w1[4];
    const float* b1[4];
    const float* w2[4];
    const float* b2[4];
};

__device__ __forceinline__ unsigned short f2bf(float f) {
    __bf16 h = (__bf16)f;
    return __builtin_bit_cast(unsigned short, h);
}

#if defined(__has_builtin)
#  if __has_builtin(__builtin_amdgcn_mfma_f32_16x16x16bf16_1k)
#    define HAVE_MFMA16 1
#  endif
#endif

__device__ __forceinline__ void mfma16(f32x4& c, u16x4 a, u16x4 b) {
#ifdef HAVE_MFMA16
    c = __builtin_amdgcn_mfma_f32_16x16x16bf16_1k(
            __builtin_bit_cast(s16x4, a), __builtin_bit_cast(s16x4, b), c, 0, 0, 0);
#else
    asm("v_mfma_f32_16x16x16_bf16 %0, %1, %2, %0" : "+v"(c) : "v"(a), "v"(b));
#endif
}

// issue async stage of slice s into ring buf[s&3]: 2 x 16B per thread (8KB per block)
__device__ __forceinline__ void stage_slice(const unsigned short* __restrict__ frag,
                                            unsigned short* wbuf, int s, int tid) {
    const unsigned short* g = frag + (size_t)s * 4096 + tid * 8;
    unsigned short* l = wbuf + (s & 3) * 4096 + tid * 8;
    __builtin_amdgcn_global_load_lds(
        (const __attribute__((address_space(1))) unsigned int*)g,
        (__attribute__((address_space(3))) unsigned int*)l, 16, 0, 0);
    __builtin_amdgcn_global_load_lds(
        (const __attribute__((address_space(1))) unsigned int*)(g + 2048),
        (__attribute__((address_space(3))) unsigned int*)(l + 2048), 16, 0, 0);
}

template <int N>
__device__ __forceinline__ void wait_bar() {
    if constexpr (N == 4)      asm volatile("s_waitcnt vmcnt(4)" ::: "memory");
    else if constexpr (N == 2) asm volatile("s_waitcnt vmcnt(2)" ::: "memory");
    else                       asm volatile("s_waitcnt vmcnt(0)" ::: "memory");
    __builtin_amdgcn_sched_barrier(0);
    __builtin_amdgcn_s_barrier();
    __builtin_amdgcn_sched_barrier(0);
}

// per-slice wait count: outstanding after wait = 2 loads per not-yet-needed slice
__device__ __forceinline__ void wait_bar_for(int S) {
    if (S <= 21)      wait_bar<4>();
    else if (S == 22) wait_bar<2>();
    else              wait_bar<0>();
}

// ---------------- prep: softmax + weights into slice-ordered fragments ----------------
// d_ws: [0..3] float softmax w; [4..67] float fused bias (sum_i w_i*b2_i);
// at byte 512: 24 slices x 4096 ushorts (8KB), consumption order:
//   branch br slices at sbase[br]={0,4,8,14}: kk[br] F1 slices then 1 F2 slice.
//   F1 slice (br,dk): e = (ks*4+mt)*512 + lane*8 + j;
//     co=mt*16+(lane&15), ci=ks*32+(lane>>4)*8+j; val = W1[co][ci][dk].
//   F2 slice (br):     e = (kb*4+mt)*256 + lane*4 + j;
//     co=mt*16+(lane&15), ci=kb*16+(lane>>4)*4+j; val = w[br]*W2[co][ci].
__global__ void prep_kernel(Ptrs p, unsigned short* __restrict__ frag, float* __restrict__ hdr) {
    int tid = threadIdx.x;
    float v0 = p.rw[0], v1 = p.rw[1], v2 = p.rw[2], v3 = p.rw[3];
    float m = fmaxf(fmaxf(v0, v1), fmaxf(v2, v3));
    float e0 = expf(v0 - m), e1 = expf(v1 - m), e2 = expf(v2 - m), e3 = expf(v3 - m);
    float s = e0 + e1 + e2 + e3;
    float w[4] = {e0 / s, e1 / s, e2 / s, e3 / s};

    if (blockIdx.x == 0) {
        if (tid < 4) hdr[tid] = w[tid];
        if (tid < 64) {
            float fb = 0.f;
            #pragma unroll
            for (int i = 0; i < 4; i++) fb += w[i] * p.b2[i][tid];
            hdr[4 + tid] = fb;
        }
    }

    const int kk[4] = {3, 3, 5, 9};
    const int sbase[4] = {0, 4, 8, 14};

    for (int idx = blockIdx.x * blockDim.x + tid; idx < NSLICE * 4096; idx += gridDim.x * blockDim.x) {
        int sl = idx >> 12;
        int e = idx & 4095;
        int br = 3;
        #pragma unroll
        for (int i = 2; i >= 0; i--) if (sl < sbase[i + 1]) br = i;
        int local = sl - sbase[br];
        unsigned short val;
        if (local < kk[br]) {       // F1 slice, dk = local
            int blk = e >> 9;       // ks*4 + mt
            int ks = blk >> 2, mt = blk & 3;
            int sub = e & 511;
            int lane = sub >> 3, j = sub & 7;
            int co = mt * 16 + (lane & 15);
            int ci = ks * 32 + (lane >> 4) * 8 + j;
            val = f2bf(p.w1[br][(co * 64 + ci) * kk[br] + local]);
        } else {                    // F2 slice
            int fi = e >> 8;        // kb*4 + mt
            int kb = fi >> 2, mt = fi & 3;
            int sub = e & 255;
            int lane = sub >> 2, j = sub & 3;
            int co = mt * 16 + (lane & 15);
            int ci = kb * 16 + (lane >> 4) * 4 + j;
            val = f2bf(w[br] * p.w2[br][co * 64 + ci]);
        }
        frag[idx] = val;
    }
}

// ---------------- main kernel ----------------
template <int KK, int PP, int S0>
__device__ __forceinline__ void do_branch(const unsigned short* __restrict__ frag,
                                          unsigned short* wbuf,
                                          const float* b1l,
                                          const unsigned short* xs,
                                          int tid, int lane, int wl0,
                                          f32x4 (&fused)[4][4]) {
    int col = lane & 15, kg = lane >> 4;

    f32x4 acc[4][4];
    #pragma unroll
    for (int mt = 0; mt < 4; mt++)
        #pragma unroll
        for (int nt = 0; nt < 4; nt++)
            acc[mt][nt] = f32x4{0.f, 0.f, 0.f, 0.f};

    #pragma unroll
    for (int dk = 0; dk < KK; dk++) {
        const int S = S0 + dk;                        // unrolled -> compile-time
        wait_bar_for(S);                              // slice S ready for all waves
        const unsigned short* wb = wbuf + (S & 3) * 4096;
        #pragma unroll
        for (int ks = 0; ks < 2; ks++) {
            bf16x8 bfr[4];
            #pragma unroll
            for (int nt = 0; nt < 4; nt++) {
                int row = wl0 + nt * 16 + col + (HALO - PP) + dk;
                bfr[nt] = __builtin_bit_cast(bf16x8, *(const u16x8*)&xs[row * RS + ks * 32 + kg * 8]);
            }
            #pragma unroll
            for (int mt = 0; mt < 4; mt++) {
                bf16x8 afr = __builtin_bit_cast(bf16x8,
                    *(const u16x8*)(wb + (ks * 4 + mt) * 512 + lane * 8));
                #pragma unroll
                for (int nt = 0; nt < 4; nt++)
                    acc[mt][nt] = __builtin_amdgcn_mfma_f32_16x16x32_bf16(afr, bfr[nt], acc[mt][nt], 0, 0, 0);
            }
        }
        if (S + 3 < NSLICE) stage_slice(frag, wbuf, S + 3, tid);   // prefetch 3 ahead
    }

    constexpr int SF2 = S0 + KK;
    f32x4 bv[4];
    #pragma unroll
    for (int mt = 0; mt < 4; mt++) bv[mt] = *(const f32x4*)&b1l[mt * 16 + kg * 4];

    wait_bar_for(SF2);
    const unsigned short* wb2 = wbuf + (SF2 & 3) * 4096;

    // conv2 (1x1) from registers: ReLU(acc+b1) repacked in-lane is the 16x16x16 B-frag.
    #pragma unroll
    for (int kb = 0; kb < 4; kb++) {
        u16x4 hb[4];
        #pragma unroll
        for (int nt = 0; nt < 4; nt++) {
            u16x4 h;
            #pragma unroll
            for (int r = 0; r < 4; r++) h[r] = f2bf(fmaxf(acc[kb][nt][r] + bv[kb][r], 0.f));
            hb[nt] = h;
        }
        #pragma unroll
        for (int mt = 0; mt < 4; mt++) {
            u16x4 afr = *(const u16x4*)(wb2 + (kb * 4 + mt) * 256 + lane * 4);
            #pragma unroll
            for (int nt = 0; nt < 4; nt++)
                mfma16(fused[mt][nt], afr, hb[nt]);
        }
    }
    if (SF2 + 3 < NSLICE) stage_slice(frag, wbuf, SF2 + 3, tid);
}

__global__ __launch_bounds__(256, 2) void wavelet_main(Ptrs p,
                                                       const unsigned short* __restrict__ frag,
                                                       const float* __restrict__ hdr,
                                                       float* __restrict__ out) {
    __shared__ unsigned short xs[XROWS * RS];   // 38016 B
    __shared__ unsigned short wbuf[4 * 4096];   // 32768 B ring for weight slices
    __shared__ float b1l[4 * 64];               // conv1 biases
    __shared__ float fbl[64];                   // fused bias sum_i w_i*b2_i

    int tid = threadIdx.x;
    int b = blockIdx.x >> 5;
    int t0 = (blockIdx.x & 31) * NT;

    // stage x tile (+halo) into LDS as bf16, zero-padded at batch edges
    {
        int c0 = (tid & 7) * 8;
        int rbase = tid >> 3;
        #pragma unroll
        for (int it = 0; it < 9; it++) {
            int rr = it * 32 + rbase;
            if (rr < XROWS) {
                int l = t0 + rr - HALO;
                u16x8 v = {0, 0, 0, 0, 0, 0, 0, 0};
                if (l >= 0 && l < Ln) {
                    const float* src = &p.x[((size_t)b * Ln + l) * 64 + c0];
                    f32x4 a0 = *(const f32x4*)src;
                    f32x4 a1 = *(const f32x4*)(src + 4);
                    #pragma unroll
                    for (int r = 0; r < 4; r++) { v[r] = f2bf(a0[r]); v[4 + r] = f2bf(a1[r]); }
                }
                *(u16x8*)&xs[rr * RS + c0] = v;
            }
        }
    }
    // biases to LDS BEFORE the weight prefetches (keeps their waits off the stage FIFO)
    b1l[tid] = p.b1[tid >> 6][tid & 63];
    if (tid < 64) fbl[tid] = hdr[4 + tid];
    __builtin_amdgcn_sched_barrier(0);

    // prologue prefetch: slices 0..2 (6 loads in flight)
    stage_slice(frag, wbuf, 0, tid);
    stage_slice(frag, wbuf, 1, tid);
    stage_slice(frag, wbuf, 2, tid);

    // xs/bias ready for all waves without draining the stage FIFO
    asm volatile("s_waitcnt lgkmcnt(0)" ::: "memory");
    __builtin_amdgcn_sched_barrier(0);
    __builtin_amdgcn_s_barrier();
    __builtin_amdgcn_sched_barrier(0);

    int lane = tid & 63;
    int wl0 = (tid >> 6) * 64;
    int kg = lane >> 4;

    f32x4 fused[4][4];
    #pragma unroll
    for (int mt = 0; mt < 4; mt++)
        #pragma unroll
        for (int nt = 0; nt < 4; nt++)
            fused[mt][nt] = f32x4{0.f, 0.f, 0.f, 0.f};

    do_branch<3, 1, 0 >(frag, wbuf, b1l + 0 * 64, xs, tid, lane, wl0, fused);
    do_branch<3, 1, 4 >(frag, wbuf, b1l + 1 * 64, xs, tid, lane, wl0, fused);
    do_branch<5, 2, 8 >(frag, wbuf, b1l + 2 * 64, xs, tid, lane, wl0, fused);
    do_branch<9, 4, 14>(frag, wbuf, b1l + 3 * 64, xs, tid, lane, wl0, fused);

#ifndef HAVE_MFMA16
    asm volatile("s_nop 7\ns_nop 7");   // MFMA->VALU hazard guard for asm path
#endif

    // epilogue: add fused bias, write out[b][l][c] fp32 channel-contiguous
    int col = lane & 15;
    f32x4 fb[4];
    #pragma unroll
    for (int mt = 0; mt < 4; mt++) fb[mt] = *(const f32x4*)&fbl[mt * 16 + kg * 4];
    #pragma unroll
    for (int mt = 0; mt < 4; mt++) {
        #pragma unroll
        for (int nt = 0; nt < 4; nt++) {
            int l = t0 + wl0 + nt * 16 + col;
            f32x4 v;
            #pragma unroll
            for (int r = 0; r < 4; r++) v[r] = fused[mt][nt][r] + fb[mt][r];
            *(f32x4*)&out[((size_t)b * Ln + l) * 64 + mt * 16 + kg * 4] = v;
        }
    }
}

extern "C" void kernel_launch(void* const* d_in, const int* in_sizes, int n_in,
                              void* d_out, int out_size, void* d_ws, size_t ws_size,
                              hipStream_t stream) {
    Ptrs p;
    p.x  = (const float*)d_in[0];
    p.rw = (const float*)d_in[1];
    for (int i = 0; i < 4; i++) {
        p.w1[i] = (const float*)d_in[2 + 4 * i];
        p.b1[i] = (const float*)d_in[3 + 4 * i];
        p.w2[i] = (const float*)d_in[4 + 4 * i];
        p.b2[i] = (const float*)d_in[5 + 4 * i];
    }
    float* hdr = (float*)d_ws;
    unsigned short* frag = (unsigned short*)((char*)d_ws + 512);

    hipLaunchKernelGGL(prep_kernel, dim3(96), dim3(256), 0, stream, p, frag, hdr);
    hipLaunchKernelGGL(wavelet_main, dim3(Bn * (Ln / NT)), dim3(256), 0, stream, p, frag, hdr,
                       (float*)d_out);
}

// Round 9
// 68.332 us; speedup vs baseline: 2.5003x; 1.0156x over previous
//
#include <hip/hip_runtime.h>

// WaveletProcessor: 4x [Conv1d(64,64,k) -> ReLU -> Conv1d(64,64,1)], softmax-weighted sum.
// Device buffers are float32. Compute: bf16 MFMA (16x16x32 conv1, 16x16x16 conv2), fp32 accum.
// Round 9: flat 24-slice software pipeline. Each period: vmcnt(2)+s_barrier, MFMAs on
// REGISTER-PREFETCHED weight frags (read last period), prefetch next slice's 8 frags
// (8x b128, uniform for F1/F2 via chunk-paired F2 layout), stage S+3 via global_load_lds.
// s_setprio around MFMA clusters. Epilogue writes full 256B lines. 2 blocks/CU.

constexpr int Bn = 32, Ln = 8192;
constexpr int NT = 256;          // length-tile per workgroup (4 waves x 64)
constexpr int HALO = 4;
constexpr int XROWS = NT + 2 * HALO;   // 264
constexpr int RS = 72;           // LDS row stride in ushorts (144B -> 2-way alias, free)
constexpr int NSLICE = 24;       // 4+4+6+10 weight slices of 8KB (4096 ushorts)

// slice descriptors: branch and dk (-1 = F2/conv2 slice)
constexpr int BRS[NSLICE] = {0,0,0,0, 1,1,1,1, 2,2,2,2,2,2, 3,3,3,3,3,3,3,3,3,3};
constexpr int DKS[NSLICE] = {0,1,2,-1, 0,1,2,-1, 0,1,2,3,4,-1, 0,1,2,3,4,5,6,7,8,-1};
constexpr int PPB[4] = {1, 1, 2, 4};

using bf16x8 = __attribute__((ext_vector_type(8))) __bf16;
using f32x4  = __attribute__((ext_vector_type(4))) float;
using u16x8  = __attribute__((ext_vector_type(8))) unsigned short;
using u16x4  = __attribute__((ext_vector_type(4))) unsigned short;
using s16x4  = __attribute__((ext_vector_type(4))) short;

struct Ptrs {
    const float* x;
    const float* rw;
    const float* w1[4];
    const float* b1[4];
    const float* w2[4];
    const float* b2[4];
};

__device__ __forceinline__ unsigned short f2bf(float f) {
    __bf16 h = (__bf16)f;
    return __builtin_bit_cast(unsigned short, h);
}

#if defined(__has_builtin)
#  if __has_builtin(__builtin_amdgcn_mfma_f32_16x16x16bf16_1k)
#    define HAVE_MFMA16 1
#  endif
#endif

__device__ __forceinline__ void mfma16(f32x4& c, u16x4 a, u16x4 b) {
#ifdef HAVE_MFMA16
    c = __builtin_amdgcn_mfma_f32_16x16x16bf16_1k(
            __builtin_bit_cast(s16x4, a), __builtin_bit_cast(s16x4, b), c, 0, 0, 0);
#else
    asm("v_mfma_f32_16x16x16_bf16 %0, %1, %2, %0" : "+v"(c) : "v"(a), "v"(b));
#endif
}

// issue async stage of slice s into ring buf[s&3]: 2 x 16B per thread (8KB per block)
__device__ __forceinline__ void stage_slice(const unsigned short* __restrict__ frag,
                                            unsigned short* wbuf, int s, int tid) {
    const unsigned short* g = frag + (size_t)s * 4096 + tid * 8;
    unsigned short* l = wbuf + (s & 3) * 4096 + tid * 8;
    __builtin_amdgcn_global_load_lds(
        (const __attribute__((address_space(1))) unsigned int*)g,
        (__attribute__((address_space(3))) unsigned int*)l, 16, 0, 0);
    __builtin_amdgcn_global_load_lds(
        (const __attribute__((address_space(1))) unsigned int*)(g + 2048),
        (__attribute__((address_space(3))) unsigned int*)(l + 2048), 16, 0, 0);
}

// ---------------- prep: softmax + weights into slice-ordered fragments ----------------
// d_ws: [0..3] float softmax w; [4..67] float fused bias (sum_i w_i*b2_i);
// at byte 512: 24 slices x 4096 ushorts (8KB). Every slice = 8 chunks of 512 ushorts,
// lane reads chunk c at c*512 + lane*8 (16B, conflict-free).
//   F1 slice (br,dk): chunk c = frag(ks,mt), c = ks*4+mt; elem lane*8+j;
//     co=mt*16+(lane&15), ci=ks*32+(lane>>4)*8+j; val = W1[co][ci][dk].
//   F2 slice (br): chunk c holds frag PAIR f=2c,2c+1 (f=kb*4+mt); elem = lane*8 + h*4 + j
//     (h=f&1); co=mt*16+(lane&15), ci=kb*16+(lane>>4)*4+j; val = w[br]*W2[co][ci].
__global__ void prep_kernel(Ptrs p, unsigned short* __restrict__ frag, float* __restrict__ hdr) {
    int tid = threadIdx.x;
    float v0 = p.rw[0], v1 = p.rw[1], v2 = p.rw[2], v3 = p.rw[3];
    float m = fmaxf(fmaxf(v0, v1), fmaxf(v2, v3));
    float e0 = expf(v0 - m), e1 = expf(v1 - m), e2 = expf(v2 - m), e3 = expf(v3 - m);
    float s = e0 + e1 + e2 + e3;
    float w[4] = {e0 / s, e1 / s, e2 / s, e3 / s};

    if (blockIdx.x == 0) {
        if (tid < 4) hdr[tid] = w[tid];
        if (tid < 64) {
            float fb = 0.f;
            #pragma unroll
            for (int i = 0; i < 4; i++) fb += w[i] * p.b2[i][tid];
            hdr[4 + tid] = fb;
        }
    }

    const int kk[4] = {3, 3, 5, 9};
    const int sbase[4] = {0, 4, 8, 14};

    for (int idx = blockIdx.x * blockDim.x + tid; idx < NSLICE * 4096; idx += gridDim.x * blockDim.x) {
        int sl = idx >> 12;
        int e = idx & 4095;
        int br = 3;
        #pragma unroll
        for (int i = 2; i >= 0; i--) if (sl < sbase[i + 1]) br = i;
        int local = sl - sbase[br];
        unsigned short val;
        if (local < kk[br]) {       // F1 slice, dk = local
            int blk = e >> 9;       // chunk = ks*4 + mt
            int ks = blk >> 2, mt = blk & 3;
            int sub = e & 511;
            int lane = sub >> 3, j = sub & 7;
            int co = mt * 16 + (lane & 15);
            int ci = ks * 32 + (lane >> 4) * 8 + j;
            val = f2bf(p.w1[br][(co * 64 + ci) * kk[br] + local]);
        } else {                    // F2 slice, chunk-paired layout
            int c = e >> 9;
            int sub = e & 511;
            int lane = sub >> 3;
            int rest = sub & 7;
            int h = rest >> 2, j = rest & 3;
            int f = c * 2 + h;      // f = kb*4 + mt
            int kb = f >> 2, mt = f & 3;
            int co = mt * 16 + (lane & 15);
            int ci = kb * 16 + (lane >> 4) * 4 + j;
            val = f2bf(w[br] * p.w2[br][co * 64 + ci]);
        }
        frag[idx] = val;
    }
}

// ---------------- main kernel: one uniform period per slice ----------------
template <int S>
__device__ __forceinline__ void period(const unsigned short* __restrict__ frag,
                                       unsigned short* wbuf,
                                       const unsigned short* xs,
                                       const float* b1l,
                                       int tid, int lane, int wl0,
                                       f32x4 (&acc)[4][4], f32x4 (&fused)[4][4],
                                       bf16x8 (&cur)[8], bf16x8 (&nxt)[8]) {
    // wait: slice S+1 staged (we read its frags this period); keep S+2 in flight
    if constexpr (S <= 21) asm volatile("s_waitcnt vmcnt(2)" ::: "memory");
    else                   asm volatile("s_waitcnt vmcnt(0)" ::: "memory");
    __builtin_amdgcn_sched_barrier(0);
    __builtin_amdgcn_s_barrier();
    __builtin_amdgcn_sched_barrier(0);

    // register-prefetch next slice's 8 weight fragments (uniform F1/F2 pattern)
    if constexpr (S + 1 < NSLICE) {
        const unsigned short* nb = wbuf + ((S + 1) & 3) * 4096 + lane * 8;
        #pragma unroll
        for (int c = 0; c < 8; c++)
            nxt[c] = __builtin_bit_cast(bf16x8, *(const u16x8*)(nb + c * 512));
    }
    if constexpr (S + 3 < NSLICE) stage_slice(frag, wbuf, S + 3, tid);

    constexpr int br = BRS[S];
    constexpr int dk = DKS[S];
    int col = lane & 15, kg = lane >> 4;

    if constexpr (dk >= 0) {
        // conv1 F1 slice
        if constexpr (dk == 0) {
            #pragma unroll
            for (int mt = 0; mt < 4; mt++)
                #pragma unroll
                for (int nt = 0; nt < 4; nt++)
                    acc[mt][nt] = f32x4{0.f, 0.f, 0.f, 0.f};
        }
        constexpr int PP = PPB[br];
        #pragma unroll
        for (int ks = 0; ks < 2; ks++) {
            bf16x8 bfr[4];
            #pragma unroll
            for (int nt = 0; nt < 4; nt++) {
                int row = wl0 + nt * 16 + col + (HALO - PP) + dk;
                bfr[nt] = __builtin_bit_cast(bf16x8, *(const u16x8*)&xs[row * RS + ks * 32 + kg * 8]);
            }
            __builtin_amdgcn_s_setprio(1);
            #pragma unroll
            for (int mt = 0; mt < 4; mt++)
                #pragma unroll
                for (int nt = 0; nt < 4; nt++)
                    acc[mt][nt] = __builtin_amdgcn_mfma_f32_16x16x32_bf16(cur[ks * 4 + mt], bfr[nt], acc[mt][nt], 0, 0, 0);
            __builtin_amdgcn_s_setprio(0);
        }
    } else {
        // conv2 F2 slice: ReLU(acc + b1) repacked in-lane is the 16x16x16 B-fragment
        const float* bb = b1l + br * 64;
        f32x4 bv[4];
        #pragma unroll
        for (int mt = 0; mt < 4; mt++) bv[mt] = *(const f32x4*)&bb[mt * 16 + kg * 4];
        #pragma unroll
        for (int kb = 0; kb < 4; kb++) {
            u16x4 hb[4];
            #pragma unroll
            for (int nt = 0; nt < 4; nt++) {
                u16x4 h;
                #pragma unroll
                for (int r = 0; r < 4; r++) h[r] = f2bf(fmaxf(acc[kb][nt][r] + bv[kb][r], 0.f));
                hb[nt] = h;
            }
            __builtin_amdgcn_s_setprio(1);
            #pragma unroll
            for (int mt2 = 0; mt2 < 4; mt2++) {
                constexpr int dummy = 0; (void)dummy;
                int f = kb * 4 + mt2;
                u16x8 u = __builtin_bit_cast(u16x8, cur[f >> 1]);
                int h4 = (f & 1) * 4;
                u16x4 afr = {u[h4], u[h4 + 1], u[h4 + 2], u[h4 + 3]};
                #pragma unroll
                for (int nt = 0; nt < 4; nt++)
                    mfma16(fused[mt2][nt], afr, hb[nt]);
            }
            __builtin_amdgcn_s_setprio(0);
        }
    }
}

template <int S>
__device__ __forceinline__ void chain(const unsigned short* __restrict__ frag,
                                      unsigned short* wbuf, const unsigned short* xs,
                                      const float* b1l, int tid, int lane, int wl0,
                                      f32x4 (&acc)[4][4], f32x4 (&fused)[4][4],
                                      bf16x8 (&A)[8], bf16x8 (&B)[8]) {
    if constexpr (S & 1) period<S>(frag, wbuf, xs, b1l, tid, lane, wl0, acc, fused, B, A);
    else                 period<S>(frag, wbuf, xs, b1l, tid, lane, wl0, acc, fused, A, B);
    if constexpr (S + 1 < NSLICE)
        chain<S + 1>(frag, wbuf, xs, b1l, tid, lane, wl0, acc, fused, A, B);
}

__global__ __launch_bounds__(256, 2) void wavelet_main(Ptrs p,
                                                       const unsigned short* __restrict__ frag,
                                                       const float* __restrict__ hdr,
                                                       float* __restrict__ out) {
    __shared__ unsigned short xs[XROWS * RS];   // 38016 B
    __shared__ unsigned short wbuf[4 * 4096];   // 32768 B ring for weight slices
    __shared__ float b1l[4 * 64];               // conv1 biases
    __shared__ float fbl[64];                   // fused bias sum_i w_i*b2_i

    int tid = threadIdx.x;
    int b = blockIdx.x >> 5;
    int t0 = (blockIdx.x & 31) * NT;

    // stage x tile (+halo) into LDS as bf16, zero-padded at batch edges
    {
        int c0 = (tid & 7) * 8;
        int rbase = tid >> 3;
        #pragma unroll
        for (int it = 0; it < 9; it++) {
            int rr = it * 32 + rbase;
            if (rr < XROWS) {
                int l = t0 + rr - HALO;
                u16x8 v = {0, 0, 0, 0, 0, 0, 0, 0};
                if (l >= 0 && l < Ln) {
                    const float* src = &p.x[((size_t)b * Ln + l) * 64 + c0];
                    f32x4 a0 = *(const f32x4*)src;
                    f32x4 a1 = *(const f32x4*)(src + 4);
                    #pragma unroll
                    for (int r = 0; r < 4; r++) { v[r] = f2bf(a0[r]); v[4 + r] = f2bf(a1[r]); }
                }
                *(u16x8*)&xs[rr * RS + c0] = v;
            }
        }
    }
    // biases to LDS BEFORE the weight prefetches (their vmem waits resolve pre-stage)
    b1l[tid] = p.b1[tid >> 6][tid & 63];
    if (tid < 64) fbl[tid] = hdr[4 + tid];
    __builtin_amdgcn_sched_barrier(0);

    // prologue prefetch: slices 0..2 (6 loads in flight)
    stage_slice(frag, wbuf, 0, tid);
    stage_slice(frag, wbuf, 1, tid);
    stage_slice(frag, wbuf, 2, tid);

    // xs/bias visible + slice 0 staged by all waves (slices 1,2 stay in flight)
    asm volatile("s_waitcnt vmcnt(4) lgkmcnt(0)" ::: "memory");
    __builtin_amdgcn_sched_barrier(0);
    __builtin_amdgcn_s_barrier();
    __builtin_amdgcn_sched_barrier(0);

    int lane = tid & 63;
    int wl0 = (tid >> 6) * 64;
    int kg = lane >> 4;

    // pre-load slice 0's weight fragments into registers
    bf16x8 A[8], B[8];
    {
        const unsigned short* b0 = wbuf + lane * 8;
        #pragma unroll
        for (int c = 0; c < 8; c++)
            A[c] = __builtin_bit_cast(bf16x8, *(const u16x8*)(b0 + c * 512));
    }

    f32x4 acc[4][4];
    f32x4 fused[4][4];
    #pragma unroll
    for (int mt = 0; mt < 4; mt++)
        #pragma unroll
        for (int nt = 0; nt < 4; nt++)
            fused[mt][nt] = f32x4{0.f, 0.f, 0.f, 0.f};

    chain<0>(frag, wbuf, xs, b1l, tid, lane, wl0, acc, fused, A, B);

#ifndef HAVE_MFMA16
    asm volatile("s_nop 7\ns_nop 7");   // MFMA->VALU hazard guard for asm path
#endif

    // epilogue: add fused bias; nt-outer so each l's 256B line is written back-to-back
    int col = lane & 15;
    f32x4 fb[4];
    #pragma unroll
    for (int mt = 0; mt < 4; mt++) fb[mt] = *(const f32x4*)&fbl[mt * 16 + kg * 4];
    #pragma unroll
    for (int nt = 0; nt < 4; nt++) {
        int l = t0 + wl0 + nt * 16 + col;
        #pragma unroll
        for (int mt = 0; mt < 4; mt++) {
            f32x4 v;
            #pragma unroll
            for (int r = 0; r < 4; r++) v[r] = fused[mt][nt][r] + fb[mt][r];
            *(f32x4*)&out[((size_t)b * Ln + l) * 64 + mt * 16 + kg * 4] = v;
        }
    }
}

extern "C" void kernel_launch(void* const* d_in, const int* in_sizes, int n_in,
                              void* d_out, int out_size, void* d_ws, size_t ws_size,
                              hipStream_t stream) {
    Ptrs p;
    p.x  = (const float*)d_in[0];
    p.rw = (const float*)d_in[1];
    for (int i = 0; i < 4; i++) {
        p.w1[i] = (const float*)d_in[2 + 4 * i];
        p.b1[i] = (const float*)d_in[3 + 4 * i];
        p.w2[i] = (const float*)d_in[4 + 4 * i];
        p.b2[i] = (const float*)d_in[5 + 4 * i];
    }
    float* hdr = (float*)d_ws;
    unsigned short* frag = (unsigned short*)((char*)d_ws + 512);

    hipLaunchKernelGGL(prep_kernel, dim3(96), dim3(256), 0, stream, p, frag, hdr);
    hipLaunchKernelGGL(wavelet_main, dim3(Bn * (Ln / NT)), dim3(256), 0, stream, p, frag, hdr,
                       (float*)d_out);
}

// Round 10
// 61.688 us; speedup vs baseline: 2.7696x; 1.1077x over previous
//
#include <hip/hip_runtime.h>

// WaveletProcessor: 4x [Conv1d(64,64,k) -> ReLU -> Conv1d(64,64,1)], softmax-weighted sum.
// Device buffers are float32. Compute: bf16 MFMA (16x16x32 conv1, 16x16x16 conv2), fp32 accum.
// Round 10: ZERO steady-state barriers. Weight fragments read directly global->VGPR
// (frag is L2-resident; 8x coalesced dwordx4 per slice), register double-buffered one
// period ahead. No wbuf/stage/vmcnt. LDS = x tile + biases only (39.3KB). Waves free-run
// and desync; LDS pipe load per period halves (bfr reads only).

constexpr int Bn = 32, Ln = 8192;
constexpr int NT = 256;          // length-tile per workgroup (4 waves x 64)
constexpr int HALO = 4;
constexpr int XROWS = NT + 2 * HALO;   // 264
constexpr int RS = 72;           // LDS row stride in ushorts (144B -> 2-way alias, free)
constexpr int NSLICE = 24;       // 4+4+6+10 weight slices of 8KB (4096 ushorts)

// slice descriptors: branch and dk (-1 = F2/conv2 slice)
constexpr int BRS[NSLICE] = {0,0,0,0, 1,1,1,1, 2,2,2,2,2,2, 3,3,3,3,3,3,3,3,3,3};
constexpr int DKS[NSLICE] = {0,1,2,-1, 0,1,2,-1, 0,1,2,3,4,-1, 0,1,2,3,4,5,6,7,8,-1};
constexpr int PPB[4] = {1, 1, 2, 4};

using bf16x8 = __attribute__((ext_vector_type(8))) __bf16;
using f32x4  = __attribute__((ext_vector_type(4))) float;
using u16x8  = __attribute__((ext_vector_type(8))) unsigned short;
using u16x4  = __attribute__((ext_vector_type(4))) unsigned short;
using s16x4  = __attribute__((ext_vector_type(4))) short;

struct Ptrs {
    const float* x;
    const float* rw;
    const float* w1[4];
    const float* b1[4];
    const float* w2[4];
    const float* b2[4];
};

__device__ __forceinline__ unsigned short f2bf(float f) {
    __bf16 h = (__bf16)f;
    return __builtin_bit_cast(unsigned short, h);
}

#if defined(__has_builtin)
#  if __has_builtin(__builtin_amdgcn_mfma_f32_16x16x16bf16_1k)
#    define HAVE_MFMA16 1
#  endif
#endif

__device__ __forceinline__ void mfma16(f32x4& c, u16x4 a, u16x4 b) {
#ifdef HAVE_MFMA16
    c = __builtin_amdgcn_mfma_f32_16x16x16bf16_1k(
            __builtin_bit_cast(s16x4, a), __builtin_bit_cast(s16x4, b), c, 0, 0, 0);
#else
    asm("v_mfma_f32_16x16x16_bf16 %0, %1, %2, %0" : "+v"(c) : "v"(a), "v"(b));
#endif
}

// ---------------- prep: softmax + weights into slice-ordered fragments ----------------
// d_ws: [0..3] float softmax w; [4..67] float fused bias (sum_i w_i*b2_i);
// at byte 512: 24 slices x 4096 ushorts (8KB). Every slice = 8 chunks of 512 ushorts,
// lane reads chunk c at c*512 + lane*8 (16B, coalesced 1KB per chunk per wave).
//   F1 slice (br,dk): chunk c = ks*4+mt; elem lane*8+j;
//     co=mt*16+(lane&15), ci=ks*32+(lane>>4)*8+j; val = W1[co][ci][dk].
//   F2 slice (br): chunk c holds frag PAIR f=2c,2c+1 (f=kb*4+mt); elem = lane*8 + h*4 + j
//     (h=f&1); co=mt*16+(lane&15), ci=kb*16+(lane>>4)*4+j; val = w[br]*W2[co][ci].
__global__ void prep_kernel(Ptrs p, unsigned short* __restrict__ frag, float* __restrict__ hdr) {
    int tid = threadIdx.x;
    float v0 = p.rw[0], v1 = p.rw[1], v2 = p.rw[2], v3 = p.rw[3];
    float m = fmaxf(fmaxf(v0, v1), fmaxf(v2, v3));
    float e0 = expf(v0 - m), e1 = expf(v1 - m), e2 = expf(v2 - m), e3 = expf(v3 - m);
    float s = e0 + e1 + e2 + e3;
    float w[4] = {e0 / s, e1 / s, e2 / s, e3 / s};

    if (blockIdx.x == 0) {
        if (tid < 4) hdr[tid] = w[tid];
        if (tid < 64) {
            float fb = 0.f;
            #pragma unroll
            for (int i = 0; i < 4; i++) fb += w[i] * p.b2[i][tid];
            hdr[4 + tid] = fb;
        }
    }

    const int kk[4] = {3, 3, 5, 9};
    const int sbase[4] = {0, 4, 8, 14};

    for (int idx = blockIdx.x * blockDim.x + tid; idx < NSLICE * 4096; idx += gridDim.x * blockDim.x) {
        int sl = idx >> 12;
        int e = idx & 4095;
        int br = 3;
        #pragma unroll
        for (int i = 2; i >= 0; i--) if (sl < sbase[i + 1]) br = i;
        int local = sl - sbase[br];
        unsigned short val;
        if (local < kk[br]) {       // F1 slice, dk = local
            int blk = e >> 9;       // chunk = ks*4 + mt
            int ks = blk >> 2, mt = blk & 3;
            int sub = e & 511;
            int lane = sub >> 3, j = sub & 7;
            int co = mt * 16 + (lane & 15);
            int ci = ks * 32 + (lane >> 4) * 8 + j;
            val = f2bf(p.w1[br][(co * 64 + ci) * kk[br] + local]);
        } else {                    // F2 slice, chunk-paired layout
            int c = e >> 9;
            int sub = e & 511;
            int lane = sub >> 3;
            int rest = sub & 7;
            int h = rest >> 2, j = rest & 3;
            int f = c * 2 + h;      // f = kb*4 + mt
            int kb = f >> 2, mt = f & 3;
            int co = mt * 16 + (lane & 15);
            int ci = kb * 16 + (lane >> 4) * 4 + j;
            val = f2bf(w[br] * p.w2[br][co * 64 + ci]);
        }
        frag[idx] = val;
    }
}

// ---------------- main kernel: one uniform period per slice, no barriers ----------------
template <int S>
__device__ __forceinline__ void period(const unsigned short* __restrict__ frag,
                                       const unsigned short* xs,
                                       const float* b1l,
                                       int lane, int wl0,
                                       f32x4 (&acc)[4][4], f32x4 (&fused)[4][4],
                                       bf16x8 (&cur)[8], bf16x8 (&nxt)[8]) {
    // issue next slice's 8 weight fragments global->reg (L2-hit, consumed next period)
    if constexpr (S + 1 < NSLICE) {
        const unsigned short* nb = frag + (size_t)(S + 1) * 4096 + lane * 8;
        #pragma unroll
        for (int c = 0; c < 8; c++)
            nxt[c] = __builtin_bit_cast(bf16x8, *(const u16x8*)(nb + c * 512));
    }

    constexpr int br = BRS[S];
    constexpr int dk = DKS[S];
    int col = lane & 15, kg = lane >> 4;

    if constexpr (dk >= 0) {
        // conv1 F1 slice
        if constexpr (dk == 0) {
            #pragma unroll
            for (int mt = 0; mt < 4; mt++)
                #pragma unroll
                for (int nt = 0; nt < 4; nt++)
                    acc[mt][nt] = f32x4{0.f, 0.f, 0.f, 0.f};
        }
        constexpr int PP = PPB[br];
        #pragma unroll
        for (int ks = 0; ks < 2; ks++) {
            bf16x8 bfr[4];
            #pragma unroll
            for (int nt = 0; nt < 4; nt++) {
                int row = wl0 + nt * 16 + col + (HALO - PP) + dk;
                bfr[nt] = __builtin_bit_cast(bf16x8, *(const u16x8*)&xs[row * RS + ks * 32 + kg * 8]);
            }
            __builtin_amdgcn_s_setprio(1);
            #pragma unroll
            for (int mt = 0; mt < 4; mt++)
                #pragma unroll
                for (int nt = 0; nt < 4; nt++)
                    acc[mt][nt] = __builtin_amdgcn_mfma_f32_16x16x32_bf16(cur[ks * 4 + mt], bfr[nt], acc[mt][nt], 0, 0, 0);
            __builtin_amdgcn_s_setprio(0);
        }
    } else {
        // conv2 F2 slice: ReLU(acc + b1) repacked in-lane is the 16x16x16 B-fragment
        const float* bb = b1l + br * 64;
        f32x4 bv[4];
        #pragma unroll
        for (int mt = 0; mt < 4; mt++) bv[mt] = *(const f32x4*)&bb[mt * 16 + kg * 4];
        #pragma unroll
        for (int kb = 0; kb < 4; kb++) {
            u16x4 hb[4];
            #pragma unroll
            for (int nt = 0; nt < 4; nt++) {
                u16x4 h;
                #pragma unroll
                for (int r = 0; r < 4; r++) h[r] = f2bf(fmaxf(acc[kb][nt][r] + bv[kb][r], 0.f));
                hb[nt] = h;
            }
            __builtin_amdgcn_s_setprio(1);
            #pragma unroll
            for (int mt2 = 0; mt2 < 4; mt2++) {
                int f = kb * 4 + mt2;
                u16x8 u = __builtin_bit_cast(u16x8, cur[f >> 1]);
                int h4 = (f & 1) * 4;
                u16x4 afr = {u[h4], u[h4 + 1], u[h4 + 2], u[h4 + 3]};
                #pragma unroll
                for (int nt = 0; nt < 4; nt++)
                    mfma16(fused[mt2][nt], afr, hb[nt]);
            }
            __builtin_amdgcn_s_setprio(0);
        }
    }
}

template <int S>
__device__ __forceinline__ void chain(const unsigned short* __restrict__ frag,
                                      const unsigned short* xs,
                                      const float* b1l, int lane, int wl0,
                                      f32x4 (&acc)[4][4], f32x4 (&fused)[4][4],
                                      bf16x8 (&A)[8], bf16x8 (&B)[8]) {
    if constexpr (S & 1) period<S>(frag, xs, b1l, lane, wl0, acc, fused, B, A);
    else                 period<S>(frag, xs, b1l, lane, wl0, acc, fused, A, B);
    if constexpr (S + 1 < NSLICE)
        chain<S + 1>(frag, xs, b1l, lane, wl0, acc, fused, A, B);
}

__global__ __launch_bounds__(256, 2) void wavelet_main(Ptrs p,
                                                       const unsigned short* __restrict__ frag,
                                                       const float* __restrict__ hdr,
                                                       float* __restrict__ out) {
    __shared__ unsigned short xs[XROWS * RS];   // 38016 B
    __shared__ float b1l[4 * 64];               // conv1 biases
    __shared__ float fbl[64];                   // fused bias sum_i w_i*b2_i

    int tid = threadIdx.x;
    int b = blockIdx.x >> 5;
    int t0 = (blockIdx.x & 31) * NT;

    // stage x tile (+halo) into LDS as bf16, zero-padded at batch edges
    {
        int c0 = (tid & 7) * 8;
        int rbase = tid >> 3;
        #pragma unroll
        for (int it = 0; it < 9; it++) {
            int rr = it * 32 + rbase;
            if (rr < XROWS) {
                int l = t0 + rr - HALO;
                u16x8 v = {0, 0, 0, 0, 0, 0, 0, 0};
                if (l >= 0 && l < Ln) {
                    const float* src = &p.x[((size_t)b * Ln + l) * 64 + c0];
                    f32x4 a0 = *(const f32x4*)src;
                    f32x4 a1 = *(const f32x4*)(src + 4);
                    #pragma unroll
                    for (int r = 0; r < 4; r++) { v[r] = f2bf(a0[r]); v[4 + r] = f2bf(a1[r]); }
                }
                *(u16x8*)&xs[rr * RS + c0] = v;
            }
        }
    }
    b1l[tid] = p.b1[tid >> 6][tid & 63];
    if (tid < 64) fbl[tid] = hdr[4 + tid];

    int lane = tid & 63;
    int wl0 = (tid >> 6) * 64;
    int kg = lane >> 4;

    // pre-load slice 0's weight fragments into registers (overlaps xs staging latency)
    bf16x8 A[8], B[8];
    {
        const unsigned short* b0 = frag + lane * 8;
        #pragma unroll
        for (int c = 0; c < 8; c++)
            A[c] = __builtin_bit_cast(bf16x8, *(const u16x8*)(b0 + c * 512));
    }

    f32x4 acc[4][4];
    f32x4 fused[4][4];
    #pragma unroll
    for (int mt = 0; mt < 4; mt++)
        #pragma unroll
        for (int nt = 0; nt < 4; nt++)
            fused[mt][nt] = f32x4{0.f, 0.f, 0.f, 0.f};

    __syncthreads();   // xs + biases ready — the ONLY barrier

    chain<0>(frag, xs, b1l, lane, wl0, acc, fused, A, B);

#ifndef HAVE_MFMA16
    asm volatile("s_nop 7\ns_nop 7");   // MFMA->VALU hazard guard for asm path
#endif

    // epilogue: add fused bias; nt-outer so each l's 256B line is written back-to-back
    int col = lane & 15;
    f32x4 fb[4];
    #pragma unroll
    for (int mt = 0; mt < 4; mt++) fb[mt] = *(const f32x4*)&fbl[mt * 16 + kg * 4];
    #pragma unroll
    for (int nt = 0; nt < 4; nt++) {
        int l = t0 + wl0 + nt * 16 + col;
        #pragma unroll
        for (int mt = 0; mt < 4; mt++) {
            f32x4 v;
            #pragma unroll
            for (int r = 0; r < 4; r++) v[r] = fused[mt][nt][r] + fb[mt][r];
            *(f32x4*)&out[((size_t)b * Ln + l) * 64 + mt * 16 + kg * 4] = v;
        }
    }
}

extern "C" void kernel_launch(void* const* d_in, const int* in_sizes, int n_in,
                              void* d_out, int out_size, void* d_ws, size_t ws_size,
                              hipStream_t stream) {
    Ptrs p;
    p.x  = (const float*)d_in[0];
    p.rw = (const float*)d_in[1];
    for (int i = 0; i < 4; i++) {
        p.w1[i] = (const float*)d_in[2 + 4 * i];
        p.b1[i] = (const float*)d_in[3 + 4 * i];
        p.w2[i] = (const float*)d_in[4 + 4 * i];
        p.b2[i] = (const float*)d_in[5 + 4 * i];
    }
    float* hdr = (float*)d_ws;
    unsigned short* frag = (unsigned short*)((char*)d_ws + 512);

    hipLaunchKernelGGL(prep_kernel, dim3(96), dim3(256), 0, stream, p, frag, hdr);
    hipLaunchKernelGGL(wavelet_main, dim3(Bn * (Ln / NT)), dim3(256), 0, stream, p, frag, hdr,
                       (float*)d_out);
}